// Round 1
// baseline (565.898 us; speedup 1.0000x reference)
//
#include <hip/hip_runtime.h>
#include <hip/hip_bf16.h>
#include <math.h>

// Shapes (from reference):
//   x1 (80,256,56,56) x2 (80,256,28,28) x3 (80,256,14,14) x4 (80,256,7,7)
//   audio (16,5,256) -> 80x256 flat
//   4 branches x 3 layers of Mamba on the 80x256 stream, then gates scale x1..x4.
// D_MODEL=256, D_INNER=512, DT_RANK=16, D_STATE=16.

#define NTOK 80          // 16*5 tokens
#define DM   256
#define DI   512

// ---- workspace layout (floats) ----
// a:     4*80*256  = 81920    @ 0
// aln:   81920               @ 81920
// xz:    4*80*1024 = 327680  @ 163840
// xc:    4*80*512  = 163840  @ 491520
// dbl:   4*80*48   = 15360   @ 655360
// dt:    163840              @ 670720
// y:     163840              @ 834560
// s:     81920               @ 998400
// total 1,080,320 floats = 4.32 MB

__device__ __forceinline__ float silu_f(float v) {
    return v / (1.f + expf(-v));
}

// ---------------- LayerNorm: one block per row ----------------
__global__ __launch_bounds__(256) void k_ln(const float* __restrict__ src, int bstride,
                                            const float* __restrict__ g,
                                            const float* __restrict__ b_,
                                            int l, float* __restrict__ aln) {
    int i = blockIdx.x / NTOK;
    int row = blockIdx.x % NTOK;
    int t = threadIdx.x;
    __shared__ float red[8];

    float x = src[(size_t)i * bstride + (size_t)row * DM + t];

    float v = x;
    for (int o = 32; o > 0; o >>= 1) v += __shfl_down(v, o, 64);
    if ((t & 63) == 0) red[t >> 6] = v;
    __syncthreads();
    float mu = (red[0] + red[1] + red[2] + red[3]) * (1.f / 256.f);
    __syncthreads();

    float dx = x - mu;
    v = dx * dx;
    for (int o = 32; o > 0; o >>= 1) v += __shfl_down(v, o, 64);
    if ((t & 63) == 0) red[t >> 6] = v;
    __syncthreads();
    float var = (red[0] + red[1] + red[2] + red[3]) * (1.f / 256.f);

    int il = i * 3 + l;
    aln[((size_t)(i * NTOK + row)) * DM + t] =
        dx * rsqrtf(var + 1e-5f) * g[il * DM + t] + b_[il * DM + t];
}

// ---------------- in_proj GEMM: xz[i] = aln[i] @ Win[i,l]^T  (80x256 @ 256x1024) ---
// grid: 4 branches * 16 ntiles(64 cols) * 4 rowgroups(20 rows) = 256 blocks
__global__ __launch_bounds__(256) void k_inproj(const float* __restrict__ aln,
                                                const float* __restrict__ Win,
                                                int l, float* __restrict__ xz) {
    int b = blockIdx.x;
    int i  = b >> 6;
    int nt = (b >> 2) & 15;
    int rg = b & 3;

    __shared__ float lds[20 * DM];
    float4* lds4 = (float4*)lds;
    const float4* src4 = (const float4*)(aln + (size_t)(i * NTOK + rg * 20) * DM);
    for (int v = threadIdx.x; v < 20 * DM / 4; v += 256) lds4[v] = src4[v];
    __syncthreads();

    int c  = nt * 64 + (threadIdx.x & 63);
    int wg = threadIdx.x >> 6;
    const float4* w4 = (const float4*)(Win + ((size_t)(i * 3 + l)) * 1024 * DM + (size_t)c * DM);

    float acc[5] = {0.f, 0.f, 0.f, 0.f, 0.f};
    for (int k = 0; k < DM / 4; ++k) {
        float4 wv = w4[k];
#pragma unroll
        for (int j = 0; j < 5; ++j) {
            float4 av = lds4[(wg * 5 + j) * (DM / 4) + k];
            acc[j] += av.x * wv.x + av.y * wv.y + av.z * wv.z + av.w * wv.w;
        }
    }
#pragma unroll
    for (int j = 0; j < 5; ++j) {
        int row = rg * 20 + wg * 5 + j;
        xz[((size_t)(i * NTOK + row)) * 1024 + c] = acc[j];
    }
}

// ---------------- conv(SiLU) + x_proj + dt_proj fused ----------------
// grid: 4 branches * 5 token-groups(16 tokens) = 20 blocks
__global__ __launch_bounds__(256) void k_conv_xproj_dt(
    const float* __restrict__ xz, const float* __restrict__ Wc,
    const float* __restrict__ bc, const float* __restrict__ Wx,
    const float* __restrict__ Wdt, const float* __restrict__ bdt,
    int l, float* __restrict__ xc_g, float* __restrict__ dbl_g,
    float* __restrict__ dt_g) {
    int blk = blockIdx.x;
    int i = blk / 5, tg = blk % 5;
    int il = i * 3 + l;

    __shared__ float xcs[16 * DI];   // 32 KB
    __shared__ float dbls[16 * 48];

    const float* xzb = xz + (size_t)i * NTOK * 1024;

    // stage 1: depthwise causal conv (k=4, left pad 3) + bias + SiLU
    for (int v = threadIdx.x; v < 16 * DI; v += 256) {
        int tt = v >> 9, d = v & (DI - 1);
        int n = tg * 16 + tt;
        int tloc = n % 5;           // position within the T=5 sequence (batch = n/5)
        float acc = 0.f;
        const float* wrow = Wc + (size_t)il * DI * 4 + d * 4;
#pragma unroll
        for (int k = 0; k < 4; ++k) {
            int ts = tloc + k - 3;
            if (ts >= 0) acc += wrow[k] * xzb[(size_t)(n + k - 3) * 1024 + d];
        }
        acc += bc[il * DI + d];
        float sv = silu_f(acc);
        xcs[v] = sv;
        xc_g[(size_t)(i * NTOK + n) * DI + d] = sv;
    }
    __syncthreads();

    // stage 2: dbl = xc @ Wx^T  (16 x 48, K=512)
    for (int o = threadIdx.x; o < 16 * 48; o += 256) {
        int tt = o / 48, c = o % 48;
        const float4* w4 = (const float4*)(Wx + (size_t)il * 48 * DI + (size_t)c * DI);
        const float4* x4 = (const float4*)(xcs + tt * DI);
        float acc = 0.f;
        for (int k = 0; k < DI / 4; ++k) {
            float4 a = x4[k], w = w4[k];
            acc += a.x * w.x + a.y * w.y + a.z * w.z + a.w * w.w;
        }
        dbls[o] = acc;
        dbl_g[(size_t)(i * NTOK + tg * 16 + tt) * 48 + c] = acc;
    }
    __syncthreads();

    // stage 3: dt = softplus(dbl[:, :16] @ Wdt^T + bdt)   (16 x 512, K=16)
    for (int v = threadIdx.x; v < 16 * DI; v += 256) {
        int tt = v >> 9, d = v & (DI - 1);
        float acc = bdt[il * DI + d];
        const float* w = Wdt + (size_t)il * DI * 16 + d * 16;
#pragma unroll
        for (int r = 0; r < 16; ++r) acc += dbls[tt * 48 + r] * w[r];
        float sp = fmaxf(acc, 0.f) + log1pf(expf(-fabsf(acc)));   // softplus, stable
        dt_g[(size_t)(i * NTOK + tg * 16 + tt) * DI + d] = sp;
    }
}

// ---------------- selective scan + D skip + z gating ----------------
// one thread per (branch, batch, channel): 4*16*512 = 32768 threads
__global__ __launch_bounds__(256) void k_scan(
    const float* __restrict__ xz, const float* __restrict__ xc_g,
    const float* __restrict__ dbl_g, const float* __restrict__ dt_g,
    const float* __restrict__ A_log, const float* __restrict__ Dp,
    int l, float* __restrict__ y_g) {
    int ch = blockIdx.x * 256 + threadIdx.x;
    int d  = ch & (DI - 1);
    int b_ = (ch >> 9) & 15;
    int i  = ch >> 13;
    int il = i * 3 + l;

    float A[16], h[16];
    const float* al = A_log + (size_t)il * DI * 16 + (size_t)d * 16;
#pragma unroll
    for (int n = 0; n < 16; ++n) { A[n] = -expf(al[n]); h[n] = 0.f; }
    float dpv = Dp[il * DI + d];

    for (int t = 0; t < 5; ++t) {
        int n = b_ * 5 + t;
        size_t base = (size_t)(i * NTOK + n);
        float dtv = dt_g[base * DI + d];
        float xv  = xc_g[base * DI + d];
        float zv  = xz[base * 1024 + DI + d];
        const float* bcrow = dbl_g + base * 48;
        float dx = dtv * xv;
        float yacc = 0.f;
#pragma unroll
        for (int nn = 0; nn < 16; ++nn) {
            float dA = expf(dtv * A[nn]);
            h[nn] = dA * h[nn] + dx * bcrow[16 + nn];
            yacc += h[nn] * bcrow[32 + nn];
        }
        float yv = yacc + xv * dpv;
        y_g[base * DI + d] = yv * silu_f(zv);
    }
}

// ---------------- out_proj GEMM + residual: a = aln + y @ Wout^T (80x512 @ 512x256)
// grid: 4 branches * 4 ntiles(64) * 4 rowgroups(20) = 64 blocks
__global__ __launch_bounds__(256) void k_outproj(const float* __restrict__ y_g,
                                                 const float* __restrict__ Wout,
                                                 const float* __restrict__ aln,
                                                 int l, float* __restrict__ a) {
    int b = blockIdx.x;
    int i  = b >> 4;
    int nt = (b >> 2) & 3;
    int rg = b & 3;

    __shared__ float lds[20 * DI];   // 40 KB
    float4* lds4 = (float4*)lds;
    const float4* src4 = (const float4*)(y_g + (size_t)(i * NTOK + rg * 20) * DI);
    for (int v = threadIdx.x; v < 20 * DI / 4; v += 256) lds4[v] = src4[v];
    __syncthreads();

    int c  = nt * 64 + (threadIdx.x & 63);
    int wg = threadIdx.x >> 6;
    const float4* w4 = (const float4*)(Wout + ((size_t)(i * 3 + l)) * DM * DI + (size_t)c * DI);

    float acc[5] = {0.f, 0.f, 0.f, 0.f, 0.f};
    for (int k = 0; k < DI / 4; ++k) {
        float4 wv = w4[k];
#pragma unroll
        for (int j = 0; j < 5; ++j) {
            float4 av = lds4[(wg * 5 + j) * (DI / 4) + k];
            acc[j] += av.x * wv.x + av.y * wv.y + av.z * wv.z + av.w * wv.w;
        }
    }
#pragma unroll
    for (int j = 0; j < 5; ++j) {
        int row = rg * 20 + wg * 5 + j;
        size_t idx = (size_t)(i * NTOK + row) * DM + c;
        a[idx] = aln[idx] + acc[j];
    }
}

// ---------------- gates: s = 1 + silu(a @ gw^T + gb), written PERMUTED ----------
// branch 0: out row n = row (b*5+t); branches 1..3: out row n = t*16 + b
__global__ __launch_bounds__(256) void k_gates(const float* __restrict__ a,
                                               const float* __restrict__ gw,
                                               const float* __restrict__ gb,
                                               float* __restrict__ s_g) {
    int b = blockIdx.x;
    int i  = b >> 4;
    int nt = (b >> 2) & 3;
    int rg = b & 3;

    __shared__ float lds[20 * DM];
    float4* lds4 = (float4*)lds;
    const float4* src4 = (const float4*)(a + (size_t)(i * NTOK + rg * 20) * DM);
    for (int v = threadIdx.x; v < 20 * DM / 4; v += 256) lds4[v] = src4[v];
    __syncthreads();

    int c  = nt * 64 + (threadIdx.x & 63);
    int wg = threadIdx.x >> 6;
    const float4* w4 = (const float4*)(gw + (size_t)i * DM * DM + (size_t)c * DM);

    float acc[5] = {0.f, 0.f, 0.f, 0.f, 0.f};
    for (int k = 0; k < DM / 4; ++k) {
        float4 wv = w4[k];
#pragma unroll
        for (int j = 0; j < 5; ++j) {
            float4 av = lds4[(wg * 5 + j) * (DM / 4) + k];
            acc[j] += av.x * wv.x + av.y * wv.y + av.z * wv.z + av.w * wv.w;
        }
    }
    float bias = gb[i * DM + c];
#pragma unroll
    for (int j = 0; j < 5; ++j) {
        int row = rg * 20 + wg * 5 + j;
        float val = acc[j] + bias;
        float g = silu_f(val);
        int np = (i == 0) ? row : (row % 5) * 16 + row / 5;
        s_g[(size_t)(i * NTOK + np) * DM + c] = 1.f + g;
    }
}

// ---------------- fused elementwise: o = x * s[plane], plane = idx / HW --------
// out layout: o4 | o3 | o2 | o1 | audio_flat
__global__ __launch_bounds__(256) void k_elem(
    const float* __restrict__ x1, const float* __restrict__ x2,
    const float* __restrict__ x3, const float* __restrict__ x4,
    const float* __restrict__ audio, const float* __restrict__ s_g,
    float* __restrict__ out) {
    int b = blockIdx.x;
    int t = threadIdx.x;

    if (b < 512) {
        // o4: HW=49 (odd) -> per-component plane index
        const float* s = s_g + 3 * NTOK * DM;
        const float4* xv = (const float4*)x4;
        float4* ov = (float4*)out;
        const int total4 = 1003520 / 4;
        for (int v = b * 256 + t; v < total4; v += 512 * 256) {
            float4 x = xv[v];
            float* xp = (float*)&x;
#pragma unroll
            for (int j = 0; j < 4; ++j) {
                int idx = v * 4 + j;
                xp[j] *= s[idx / 49];
            }
            ov[v] = x;
        }
    } else if (b < 1024) {
        // o3: HW=196, HW4=49
        const float* s = s_g + 2 * NTOK * DM;
        const float4* xv = (const float4*)x3;
        float4* ov = (float4*)(out + 1003520);
        const int total4 = 4014080 / 4;
        for (int v = (b - 512) * 256 + t; v < total4; v += 512 * 256) {
            float f = s[v / 49];
            float4 x = xv[v];
            x.x *= f; x.y *= f; x.z *= f; x.w *= f;
            ov[v] = x;
        }
    } else if (b < 2048) {
        // o2: HW=784, HW4=196
        const float* s = s_g + 1 * NTOK * DM;
        const float4* xv = (const float4*)x2;
        float4* ov = (float4*)(out + 5017600);
        const int total4 = 16056320 / 4;
        for (int v = (b - 1024) * 256 + t; v < total4; v += 1024 * 256) {
            float f = s[v / 196];
            float4 x = xv[v];
            x.x *= f; x.y *= f; x.z *= f; x.w *= f;
            ov[v] = x;
        }
    } else if (b < 6144) {
        // o1: HW=3136, HW4=784
        const float* s = s_g;
        const float4* xv = (const float4*)x1;
        float4* ov = (float4*)(out + 21073920);
        const int total4 = 64225280 / 4;
        for (int v = (b - 2048) * 256 + t; v < total4; v += 4096 * 256) {
            float f = s[v / 784];
            float4 x = xv[v];
            x.x *= f; x.y *= f; x.z *= f; x.w *= f;
            ov[v] = x;
        }
    } else {
        // audio passthrough: 20480 floats
        int idx = (b - 6144) * 256 + t;
        out[85299200 + idx] = audio[idx];
    }
}

extern "C" void kernel_launch(void* const* d_in, const int* in_sizes, int n_in,
                              void* d_out, int out_size, void* d_ws, size_t ws_size,
                              hipStream_t stream) {
    const float* x1        = (const float*)d_in[0];
    const float* x2        = (const float*)d_in[1];
    const float* x3        = (const float*)d_in[2];
    const float* x4        = (const float*)d_in[3];
    const float* audio     = (const float*)d_in[4];
    const float* ln_g      = (const float*)d_in[5];
    const float* ln_b      = (const float*)d_in[6];
    const float* in_proj_w = (const float*)d_in[7];
    const float* conv_w    = (const float*)d_in[8];
    const float* conv_b    = (const float*)d_in[9];
    const float* xproj_w   = (const float*)d_in[10];
    const float* dt_w      = (const float*)d_in[11];
    const float* dt_b      = (const float*)d_in[12];
    const float* A_log     = (const float*)d_in[13];
    const float* Dvec      = (const float*)d_in[14];
    const float* out_proj_w= (const float*)d_in[15];
    const float* gate_w    = (const float*)d_in[16];
    const float* gate_b    = (const float*)d_in[17];

    float* ws  = (float*)d_ws;
    float* a    = ws + 0;
    float* aln  = ws + 81920;
    float* xz   = ws + 163840;
    float* xc   = ws + 491520;
    float* dbl  = ws + 655360;
    float* dtb  = ws + 670720;
    float* y    = ws + 834560;
    float* sg   = ws + 998400;

    for (int l = 0; l < 3; ++l) {
        const float* src = (l == 0) ? audio : a;
        int bstride = (l == 0) ? 0 : NTOK * DM;
        k_ln<<<4 * NTOK, 256, 0, stream>>>(src, bstride, ln_g, ln_b, l, aln);
        k_inproj<<<256, 256, 0, stream>>>(aln, in_proj_w, l, xz);
        k_conv_xproj_dt<<<20, 256, 0, stream>>>(xz, conv_w, conv_b, xproj_w,
                                                dt_w, dt_b, l, xc, dbl, dtb);
        k_scan<<<128, 256, 0, stream>>>(xz, xc, dbl, dtb, A_log, Dvec, l, y);
        k_outproj<<<64, 256, 0, stream>>>(y, out_proj_w, aln, l, a);
    }
    k_gates<<<64, 256, 0, stream>>>(a, gate_w, gate_b, sg);
    k_elem<<<6224, 256, 0, stream>>>(x1, x2, x3, x4, audio, sg, (float*)d_out);
}

// Round 2
// 421.788 us; speedup vs baseline: 1.3417x; 1.3417x over previous
//
#include <hip/hip_runtime.h>
#include <hip/hip_bf16.h>
#include <math.h>

// x1 (80,256,56,56) x2 (80,256,28,28) x3 (80,256,14,14) x4 (80,256,7,7)
// audio (16,5,256) -> 4 branches x 3 mamba layers -> gates scale x1..x4.
// Whole chain decomposes into 64 independent (branch, batch) problems:
// LN/GEMMs per-token, conv causal within 5-token batch, scan per-batch.
// => one fused kernel, 1 block per (branch,batch), LDS-resident intermediates.

#define NTOK 80
#define DM   256
#define DI   512

__device__ __forceinline__ float silu_f(float v) {
    return v / (1.f + expf(-v));
}
__device__ __forceinline__ float dot4(float4 a, float4 b) {
    return a.x*b.x + a.y*b.y + a.z*b.z + a.w*b.w;
}

// ---------------- fused mamba chain + gates: 64 blocks x 1024 threads ----------
__global__ __launch_bounds__(1024) void k_chain(
    const float* __restrict__ audio,
    const float* __restrict__ ln_g, const float* __restrict__ ln_b,
    const float* __restrict__ Win,  const float* __restrict__ Wc,
    const float* __restrict__ bc,   const float* __restrict__ Wx,
    const float* __restrict__ Wdt,  const float* __restrict__ bdt,
    const float* __restrict__ Alog, const float* __restrict__ Dp,
    const float* __restrict__ Wout, const float* __restrict__ gw,
    const float* __restrict__ gb,   float* __restrict__ s_g)
{
    int i = blockIdx.x >> 4;      // branch 0..3
    int b = blockIdx.x & 15;      // batch 0..15
    int tid  = threadIdx.x;
    int lane = tid & 63;
    int wave = tid >> 6;

    __shared__ float a_s  [5*DM];     // current activations (5 tokens x 256)
    __shared__ float aln_s[5*DM];     // LN output (residual base)
    __shared__ float xz_s [5*1024];   // in_proj out; reused as outproj partials
    __shared__ float xc_s [5*DI];     // conv+silu out
    __shared__ float dbl_s[5*48];     // x_proj out (dt_in | B | C)
    __shared__ float dt_s [5*DI];     // softplus(dt)
    __shared__ float y_s  [5*DI];     // scan out * silu(z)

    // load this batch's 5 audio rows
    if (tid < 320)
        ((float4*)a_s)[tid] = ((const float4*)(audio + (size_t)b*5*DM))[tid];
    __syncthreads();

    for (int l = 0; l < 3; ++l) {
        int il = i*3 + l;

        // ---- LayerNorm: wave w < 5 handles row w (4 floats per lane) ----
        if (wave < 5) {
            float4 x = ((float4*)a_s)[wave*64 + lane];
            float s = x.x + x.y + x.z + x.w;
            #pragma unroll
            for (int o = 32; o > 0; o >>= 1) s += __shfl_down(s, o, 64);
            float mu = __shfl(s, 0, 64) * (1.f/256.f);
            float4 d = make_float4(x.x-mu, x.y-mu, x.z-mu, x.w-mu);
            float v = d.x*d.x + d.y*d.y + d.z*d.z + d.w*d.w;
            #pragma unroll
            for (int o = 32; o > 0; o >>= 1) v += __shfl_down(v, o, 64);
            float rstd = rsqrtf(__shfl(v, 0, 64) * (1.f/256.f) + 1e-5f);
            float4 g4 = ((const float4*)(ln_g + (size_t)il*DM))[lane];
            float4 b4 = ((const float4*)(ln_b + (size_t)il*DM))[lane];
            float4 o4 = make_float4(d.x*rstd*g4.x + b4.x,
                                    d.y*rstd*g4.y + b4.y,
                                    d.z*rstd*g4.z + b4.z,
                                    d.w*rstd*g4.w + b4.w);
            ((float4*)aln_s)[wave*64 + lane] = o4;
        }
        __syncthreads();

        // ---- in_proj: column c = tid (0..1023), 5 rows, K=256 ----
        {
            const float4* w4 = (const float4*)(Win + ((size_t)il*1024 + tid)*DM);
            const float4* a4 = (const float4*)aln_s;
            float acc[5] = {0.f,0.f,0.f,0.f,0.f};
            #pragma unroll 4
            for (int k = 0; k < 64; ++k) {
                float4 w = w4[k];
                #pragma unroll
                for (int j = 0; j < 5; ++j)
                    acc[j] += dot4(a4[j*64 + k], w);
            }
            #pragma unroll
            for (int j = 0; j < 5; ++j) xz_s[j*1024 + tid] = acc[j];
        }
        __syncthreads();

        // ---- depthwise causal conv (k=4) + bias + SiLU ----
        for (int v = tid; v < 5*DI; v += 1024) {
            int r = v >> 9, d = v & (DI-1);
            float acc = bc[(size_t)il*DI + d];
            const float* wr = Wc + ((size_t)il*DI + d)*4;
            #pragma unroll
            for (int k = 0; k < 4; ++k) {
                int ts = r + k - 3;
                if (ts >= 0) acc += wr[k] * xz_s[ts*1024 + d];
            }
            xc_s[r*DI + d] = silu_f(acc);
        }
        __syncthreads();

        // ---- x_proj: 5x48, K=512 ----
        if (tid < 240) {
            int r = tid / 48, c = tid % 48;
            const float4* w4 = (const float4*)(Wx + ((size_t)il*48 + c)*DI);
            const float4* x4 = (const float4*)(xc_s + r*DI);
            float acc = 0.f;
            #pragma unroll 8
            for (int k = 0; k < 128; ++k) acc += dot4(x4[k], w4[k]);
            dbl_s[r*48 + c] = acc;
        }
        __syncthreads();

        // ---- dt = softplus(dbl[:, :16] @ Wdt^T + bdt) ----
        for (int v = tid; v < 5*DI; v += 1024) {
            int r = v >> 9, d = v & (DI-1);
            float acc = bdt[(size_t)il*DI + d];
            const float* w = Wdt + ((size_t)il*DI + d)*16;
            #pragma unroll
            for (int j = 0; j < 16; ++j) acc += dbl_s[r*48 + j] * w[j];
            dt_s[r*DI + d] = fmaxf(acc, 0.f) + log1pf(expf(-fabsf(acc)));
        }
        __syncthreads();

        // ---- selective scan + D skip + z gate: thread = channel ----
        if (tid < DI) {
            int d = tid;
            float A[16], h[16];
            const float* al = Alog + ((size_t)il*DI + d)*16;
            #pragma unroll
            for (int n = 0; n < 16; ++n) { A[n] = -expf(al[n]); h[n] = 0.f; }
            float dv = Dp[(size_t)il*DI + d];
            #pragma unroll
            for (int t = 0; t < 5; ++t) {
                float dtv = dt_s[t*DI + d];
                float xv  = xc_s[t*DI + d];
                float zv  = xz_s[t*1024 + DI + d];
                float dx  = dtv * xv;
                float yacc = 0.f;
                #pragma unroll
                for (int n = 0; n < 16; ++n) {
                    h[n] = expf(dtv*A[n])*h[n] + dx*dbl_s[t*48 + 16 + n];
                    yacc += h[n]*dbl_s[t*48 + 32 + n];
                }
                y_s[t*DI + d] = (yacc + xv*dv) * silu_f(zv);
            }
        }
        __syncthreads();   // scan done: xz_s free for reuse, y_s ready

        // ---- out_proj, K split 4 ways; partials into xz_s[kq][row][col] ----
        {
            int c  = tid & 255;
            int kq = tid >> 8;
            const float4* w4 = (const float4*)(Wout + ((size_t)il*DM + c)*DI) + kq*32;
            const float4* yy = (const float4*)y_s;
            float acc[5] = {0.f,0.f,0.f,0.f,0.f};
            #pragma unroll 4
            for (int k = 0; k < 32; ++k) {
                float4 w = w4[k];
                #pragma unroll
                for (int j = 0; j < 5; ++j)
                    acc[j] += dot4(yy[j*128 + kq*32 + k], w);
            }
            #pragma unroll
            for (int j = 0; j < 5; ++j)
                xz_s[(kq*5 + j)*256 + c] = acc[j];
        }
        __syncthreads();

        // ---- reduce partials + residual (a = aln + mamba_out) ----
        for (int v = tid; v < 5*DM; v += 1024) {
            int r = v >> 8, c = v & 255;
            float sum = aln_s[r*DM + c];
            #pragma unroll
            for (int kq = 0; kq < 4; ++kq) sum += xz_s[(kq*5 + r)*256 + c];
            a_s[r*DM + c] = sum;
        }
        __syncthreads();
    }

    // ---- gates: s = 1 + silu(a @ gw^T + gb), written permuted ----
    for (int v = tid; v < 5*DM; v += 1024) {
        int r = v >> 8, c = v & 255;
        const float4* w4 = (const float4*)(gw + ((size_t)i*DM + c)*DM);
        const float4* a4 = (const float4*)(a_s + r*DM);
        float acc = gb[(size_t)i*DM + c];
        #pragma unroll 8
        for (int k = 0; k < 64; ++k) acc += dot4(a4[k], w4[k]);
        int row = b*5 + r;
        int np  = (i == 0) ? row : (r*16 + b);
        s_g[((size_t)i*NTOK + np)*DM + c] = 1.f + silu_f(acc);
    }
}

// ---------------- fused elementwise: o = x * s[plane], plane = idx / HW --------
__global__ __launch_bounds__(256) void k_elem(
    const float* __restrict__ x1, const float* __restrict__ x2,
    const float* __restrict__ x3, const float* __restrict__ x4,
    const float* __restrict__ audio, const float* __restrict__ s_g,
    float* __restrict__ out) {
    int b = blockIdx.x;
    int t = threadIdx.x;

    if (b < 512) {
        // o4: HW=49 (odd) -> per-component plane index
        const float* s = s_g + 3 * NTOK * DM;
        const float4* xv = (const float4*)x4;
        float4* ov = (float4*)out;
        const int total4 = 1003520 / 4;
        for (int v = b * 256 + t; v < total4; v += 512 * 256) {
            float4 x = xv[v];
            float* xp = (float*)&x;
#pragma unroll
            for (int j = 0; j < 4; ++j) {
                int idx = v * 4 + j;
                xp[j] *= s[idx / 49];
            }
            ov[v] = x;
        }
    } else if (b < 1024) {
        // o3: HW=196, HW4=49
        const float* s = s_g + 2 * NTOK * DM;
        const float4* xv = (const float4*)x3;
        float4* ov = (float4*)(out + 1003520);
        const int total4 = 4014080 / 4;
        for (int v = (b - 512) * 256 + t; v < total4; v += 512 * 256) {
            float f = s[v / 49];
            float4 x = xv[v];
            x.x *= f; x.y *= f; x.z *= f; x.w *= f;
            ov[v] = x;
        }
    } else if (b < 2048) {
        // o2: HW=784, HW4=196
        const float* s = s_g + 1 * NTOK * DM;
        const float4* xv = (const float4*)x2;
        float4* ov = (float4*)(out + 5017600);
        const int total4 = 16056320 / 4;
        for (int v = (b - 1024) * 256 + t; v < total4; v += 1024 * 256) {
            float f = s[v / 196];
            float4 x = xv[v];
            x.x *= f; x.y *= f; x.z *= f; x.w *= f;
            ov[v] = x;
        }
    } else if (b < 6144) {
        // o1: HW=3136, HW4=784
        const float* s = s_g;
        const float4* xv = (const float4*)x1;
        float4* ov = (float4*)(out + 21073920);
        const int total4 = 64225280 / 4;
        for (int v = (b - 2048) * 256 + t; v < total4; v += 4096 * 256) {
            float f = s[v / 784];
            float4 x = xv[v];
            x.x *= f; x.y *= f; x.z *= f; x.w *= f;
            ov[v] = x;
        }
    } else {
        // audio passthrough: 20480 floats
        int idx = (b - 6144) * 256 + t;
        out[85299200 + idx] = audio[idx];
    }
}

extern "C" void kernel_launch(void* const* d_in, const int* in_sizes, int n_in,
                              void* d_out, int out_size, void* d_ws, size_t ws_size,
                              hipStream_t stream) {
    const float* x1        = (const float*)d_in[0];
    const float* x2        = (const float*)d_in[1];
    const float* x3        = (const float*)d_in[2];
    const float* x4        = (const float*)d_in[3];
    const float* audio     = (const float*)d_in[4];
    const float* ln_g      = (const float*)d_in[5];
    const float* ln_b      = (const float*)d_in[6];
    const float* in_proj_w = (const float*)d_in[7];
    const float* conv_w    = (const float*)d_in[8];
    const float* conv_b    = (const float*)d_in[9];
    const float* xproj_w   = (const float*)d_in[10];
    const float* dt_w      = (const float*)d_in[11];
    const float* dt_b      = (const float*)d_in[12];
    const float* A_log     = (const float*)d_in[13];
    const float* Dvec      = (const float*)d_in[14];
    const float* out_proj_w= (const float*)d_in[15];
    const float* gate_w    = (const float*)d_in[16];
    const float* gate_b    = (const float*)d_in[17];

    float* sg = (float*)d_ws;   // 4*80*256 floats

    k_chain<<<64, 1024, 0, stream>>>(audio, ln_g, ln_b, in_proj_w, conv_w,
                                     conv_b, xproj_w, dt_w, dt_b, A_log, Dvec,
                                     out_proj_w, gate_w, gate_b, sg);
    k_elem<<<6224, 256, 0, stream>>>(x1, x2, x3, x4, audio, sg, (float*)d_out);
}

// Round 3
// 320.979 us; speedup vs baseline: 1.7630x; 1.3141x over previous
//
#include <hip/hip_runtime.h>
#include <hip/hip_bf16.h>
#include <math.h>

// x1 (80,256,56,56) x2 (80,256,28,28) x3 (80,256,14,14) x4 (80,256,7,7)
// audio (16,5,256) -> 4 branches x 3 mamba layers -> gates scale x1..x4.
// 64 independent (branch,batch) problems -> 1 block each, LDS-resident chain.
// Weights pre-transposed to k-major so GEMV weight loads are lane-coalesced.

#define NTOK 80
#define DM   256
#define DI   512

__device__ __forceinline__ float silu_f(float v) {
    return v / (1.f + expf(-v));
}

// ---- workspace layout (floats) ----
// sg    81920        @ 0
// WinT  12*262144    @ 81920     [256 k][1024 c] per (i,l)
// WoutT 12*131072    @ 3227648   [512 k][256 c]
// WxT   12*24576     @ 4800512   [512 k][48 c]
// gwT   4*65536      @ 5095424   [256 k][256 c]
#define OFF_SG    0
#define OFF_WINT  81920
#define OFF_WOUTT 3227648
#define OFF_WXT   4800512
#define OFF_GWT   5095424

// ---------------- weight transpose: 32x32 LDS tiles, coalesced both ways ------
__global__ __launch_bounds__(256) void k_tr(const float* __restrict__ Win,
                                            const float* __restrict__ Wout,
                                            const float* __restrict__ Wx,
                                            const float* __restrict__ gw,
                                            float* __restrict__ ws) {
    int b = blockIdx.x;
    const float* src; float* dst; int R, C, tile;
    if (b < 3072) {                       // Win: 12 x (1024 x 256)
        int mat = b >> 8; tile = b & 255; R = 1024; C = 256;
        src = Win + (size_t)mat * R * C; dst = ws + OFF_WINT + (size_t)mat * R * C;
    } else if (b < 4608) {                // Wout: 12 x (256 x 512)
        b -= 3072; int mat = b >> 7; tile = b & 127; R = 256; C = 512;
        src = Wout + (size_t)mat * R * C; dst = ws + OFF_WOUTT + (size_t)mat * R * C;
    } else if (b < 4992) {                // Wx: 12 x (48 x 512)
        b -= 4608; int mat = b >> 5; tile = b & 31; R = 48; C = 512;
        src = Wx + (size_t)mat * R * C; dst = ws + OFF_WXT + (size_t)mat * R * C;
    } else {                              // gw: 4 x (256 x 256)
        b -= 4992; int mat = b >> 6; tile = b & 63; R = 256; C = 256;
        src = gw + (size_t)mat * R * C; dst = ws + OFF_GWT + (size_t)mat * R * C;
    }
    int tilesC = C >> 5;
    int r0 = (tile / tilesC) << 5, c0 = (tile % tilesC) << 5;
    __shared__ float t[32][33];
    int tx = threadIdx.x & 31, ty = threadIdx.x >> 5;
#pragma unroll
    for (int j = 0; j < 4; ++j) {
        int r = ty + j * 8;
        if (r0 + r < R) t[r][tx] = src[(size_t)(r0 + r) * C + c0 + tx];
    }
    __syncthreads();
#pragma unroll
    for (int j = 0; j < 4; ++j) {
        int c = ty + j * 8;
        if (r0 + tx < R) dst[(size_t)(c0 + c) * R + r0 + tx] = t[tx][c];
    }
}

// ---------------- fused mamba chain + gates: 64 blocks x 1024 threads ----------
__global__ __launch_bounds__(1024, 4) void k_chain(
    const float* __restrict__ audio,
    const float* __restrict__ ln_g, const float* __restrict__ ln_b,
    const float* __restrict__ Wc,   const float* __restrict__ bc,
    const float* __restrict__ Wdt,  const float* __restrict__ bdt,
    const float* __restrict__ Alog, const float* __restrict__ Dp,
    const float* __restrict__ gb,   float* __restrict__ ws)
{
    // XCD swizzle: branch i -> XCD slots {2i, 2i+1} (assuming XCD = blockIdx%8)
    int g = blockIdx.x;
    int slot = g & 7;
    int i = slot >> 1;                 // branch 0..3
    int b = ((g >> 3) << 1) | (slot & 1);   // batch 0..15
    int tid  = threadIdx.x;
    int lane = tid & 63;
    int wave = tid >> 6;

    const float* WinT  = ws + OFF_WINT;
    const float* WoutT = ws + OFF_WOUTT;
    const float* WxT   = ws + OFF_WXT;
    const float* gwT   = ws + OFF_GWT;
    float* s_g         = ws + OFF_SG;

    __shared__ float a_s  [5*DM];     // current activations
    __shared__ float aln_s[5*DM];     // LN output (residual base)
    __shared__ float xz_s [5*1024];   // in_proj out; reused as partial buffers
    __shared__ float xc_s [5*DI];     // conv+silu out
    __shared__ float dbl_s[5*48];     // x_proj out (dt_in | B | C)
    __shared__ float dt_s [5*DI];     // softplus(dt)
    __shared__ float y_s  [5*DI];     // scan out * silu(z)
    __shared__ float xp_s [4*5*48];   // x_proj partials

    if (tid < 320)
        ((float4*)a_s)[tid] = ((const float4*)(audio + (size_t)b*5*DM))[tid];
    __syncthreads();

    for (int l = 0; l < 3; ++l) {
        int il = i*3 + l;

        // ---- LayerNorm: wave w < 5 handles row w ----
        if (wave < 5) {
            float4 x = ((float4*)a_s)[wave*64 + lane];
            float s = x.x + x.y + x.z + x.w;
            #pragma unroll
            for (int o = 32; o > 0; o >>= 1) s += __shfl_down(s, o, 64);
            float mu = __shfl(s, 0, 64) * (1.f/256.f);
            float4 d = make_float4(x.x-mu, x.y-mu, x.z-mu, x.w-mu);
            float v = d.x*d.x + d.y*d.y + d.z*d.z + d.w*d.w;
            #pragma unroll
            for (int o = 32; o > 0; o >>= 1) v += __shfl_down(v, o, 64);
            float rstd = rsqrtf(__shfl(v, 0, 64) * (1.f/256.f) + 1e-5f);
            float4 g4 = ((const float4*)(ln_g + (size_t)il*DM))[lane];
            float4 b4 = ((const float4*)(ln_b + (size_t)il*DM))[lane];
            ((float4*)aln_s)[wave*64 + lane] =
                make_float4(d.x*rstd*g4.x + b4.x, d.y*rstd*g4.y + b4.y,
                            d.z*rstd*g4.z + b4.z, d.w*rstd*g4.w + b4.w);
        }
        __syncthreads();

        // ---- in_proj: col c = tid, K=256; weights k-major (coalesced) ----
        {
            const float* w = WinT + (size_t)il*1024*256 + tid;
            const float4* a4 = (const float4*)aln_s;
            float ac0=0.f, ac1=0.f, ac2=0.f, ac3=0.f, ac4=0.f;
            #pragma unroll 4
            for (int k4 = 0; k4 < 64; ++k4) {
                float4 A0 = a4[k4], A1 = a4[64+k4], A2 = a4[128+k4],
                       A3 = a4[192+k4], A4 = a4[256+k4];
                float w0 = w[(4*k4+0)*1024], w1 = w[(4*k4+1)*1024],
                      w2 = w[(4*k4+2)*1024], w3 = w[(4*k4+3)*1024];
                ac0 = fmaf(w3,A0.w,fmaf(w2,A0.z,fmaf(w1,A0.y,fmaf(w0,A0.x,ac0))));
                ac1 = fmaf(w3,A1.w,fmaf(w2,A1.z,fmaf(w1,A1.y,fmaf(w0,A1.x,ac1))));
                ac2 = fmaf(w3,A2.w,fmaf(w2,A2.z,fmaf(w1,A2.y,fmaf(w0,A2.x,ac2))));
                ac3 = fmaf(w3,A3.w,fmaf(w2,A3.z,fmaf(w1,A3.y,fmaf(w0,A3.x,ac3))));
                ac4 = fmaf(w3,A4.w,fmaf(w2,A4.z,fmaf(w1,A4.y,fmaf(w0,A4.x,ac4))));
            }
            xz_s[       tid] = ac0;  xz_s[1024 + tid] = ac1;
            xz_s[2048 + tid] = ac2;  xz_s[3072 + tid] = ac3;
            xz_s[4096 + tid] = ac4;
        }
        __syncthreads();

        // ---- depthwise causal conv (k=4) + bias + SiLU ----
        for (int v = tid; v < 5*DI; v += 1024) {
            int r = v >> 9, d = v & (DI-1);
            float acc = bc[(size_t)il*DI + d];
            const float* wr = Wc + ((size_t)il*DI + d)*4;
            #pragma unroll
            for (int k = 0; k < 4; ++k) {
                int ts = r + k - 3;
                if (ts >= 0) acc += wr[k] * xz_s[ts*1024 + d];
            }
            xc_s[r*DI + d] = silu_f(acc);
        }
        __syncthreads();

        // ---- x_proj: 5x48, K=512 split 4 ways over 960 threads ----
        if (tid < 960) {
            int c = tid % 48, r = (tid / 48) % 5, kq = tid / 240;
            const float* w  = WxT + (size_t)il*512*48 + c;
            const float* xr = xc_s + r*DI + kq*128;
            float acc = 0.f;
            #pragma unroll 4
            for (int k = 0; k < 128; ++k) acc = fmaf(w[(kq*128+k)*48], xr[k], acc);
            xp_s[tid] = acc;
        }
        __syncthreads();
        if (tid < 240)
            dbl_s[tid] = xp_s[tid] + xp_s[240+tid] + xp_s[480+tid] + xp_s[720+tid];
        __syncthreads();

        // ---- dt = softplus(dbl[:, :16] @ Wdt^T + bdt) ----
        for (int v = tid; v < 5*DI; v += 1024) {
            int r = v >> 9, d = v & (DI-1);
            float acc = bdt[(size_t)il*DI + d];
            const float* w = Wdt + ((size_t)il*DI + d)*16;
            #pragma unroll
            for (int j = 0; j < 16; ++j) acc += dbl_s[r*48 + j] * w[j];
            dt_s[r*DI + d] = fmaxf(acc, 0.f) + log1pf(expf(-fabsf(acc)));
        }
        __syncthreads();

        // ---- selective scan + D skip + z gate: thread = channel ----
        if (tid < DI) {
            int d = tid;
            float A[16], h[16];
            const float* al = Alog + ((size_t)il*DI + d)*16;
            #pragma unroll
            for (int n = 0; n < 16; ++n) { A[n] = -expf(al[n]); h[n] = 0.f; }
            float dv = Dp[(size_t)il*DI + d];
            #pragma unroll
            for (int t = 0; t < 5; ++t) {
                float dtv = dt_s[t*DI + d];
                float xv  = xc_s[t*DI + d];
                float zv  = xz_s[t*1024 + DI + d];
                float dx  = dtv * xv;
                float yacc = 0.f;
                #pragma unroll
                for (int n = 0; n < 16; ++n) {
                    h[n] = expf(dtv*A[n])*h[n] + dx*dbl_s[t*48 + 16 + n];
                    yacc += h[n]*dbl_s[t*48 + 32 + n];
                }
                y_s[t*DI + d] = (yacc + xv*dv) * silu_f(zv);
            }
        }
        __syncthreads();   // xz_s free, y_s ready

        // ---- out_proj: c = tid&255, K split 4; weights k-major ----
        {
            int c = tid & 255, kq = tid >> 8;
            const float* w = WoutT + (size_t)il*512*256 + c;
            const float4* yy = (const float4*)y_s;   // [5][128]
            float ac0=0.f, ac1=0.f, ac2=0.f, ac3=0.f, ac4=0.f;
            #pragma unroll 4
            for (int k4 = 0; k4 < 32; ++k4) {
                int kb = kq*32 + k4;
                float4 Y0 = yy[kb], Y1 = yy[128+kb], Y2 = yy[256+kb],
                       Y3 = yy[384+kb], Y4 = yy[512+kb];
                float w0 = w[(4*kb+0)*256], w1 = w[(4*kb+1)*256],
                      w2 = w[(4*kb+2)*256], w3 = w[(4*kb+3)*256];
                ac0 = fmaf(w3,Y0.w,fmaf(w2,Y0.z,fmaf(w1,Y0.y,fmaf(w0,Y0.x,ac0))));
                ac1 = fmaf(w3,Y1.w,fmaf(w2,Y1.z,fmaf(w1,Y1.y,fmaf(w0,Y1.x,ac1))));
                ac2 = fmaf(w3,Y2.w,fmaf(w2,Y2.z,fmaf(w1,Y2.y,fmaf(w0,Y2.x,ac2))));
                ac3 = fmaf(w3,Y3.w,fmaf(w2,Y3.z,fmaf(w1,Y3.y,fmaf(w0,Y3.x,ac3))));
                ac4 = fmaf(w3,Y4.w,fmaf(w2,Y4.z,fmaf(w1,Y4.y,fmaf(w0,Y4.x,ac4))));
            }
            xz_s[(kq*5+0)*256+c] = ac0;  xz_s[(kq*5+1)*256+c] = ac1;
            xz_s[(kq*5+2)*256+c] = ac2;  xz_s[(kq*5+3)*256+c] = ac3;
            xz_s[(kq*5+4)*256+c] = ac4;
        }
        __syncthreads();

        // ---- reduce partials + residual ----
        for (int v = tid; v < 5*DM; v += 1024) {
            int r = v >> 8, c = v & 255;
            float sum = aln_s[r*DM + c];
            #pragma unroll
            for (int kq = 0; kq < 4; ++kq) sum += xz_s[(kq*5 + r)*256 + c];
            a_s[r*DM + c] = sum;
        }
        __syncthreads();
    }

    // ---- gates: c = tid&255, K=256 split 4; s = 1+silu(a@gw^T+gb), permuted ----
    {
        int c = tid & 255, kq = tid >> 8;
        const float* w = gwT + (size_t)i*256*256 + c;
        const float4* a4 = (const float4*)a_s;   // [5][64]
        float ac0=0.f, ac1=0.f, ac2=0.f, ac3=0.f, ac4=0.f;
        #pragma unroll 4
        for (int k4 = 0; k4 < 16; ++k4) {
            int kb = kq*16 + k4;
            float4 A0 = a4[kb], A1 = a4[64+kb], A2 = a4[128+kb],
                   A3 = a4[192+kb], A4 = a4[256+kb];
            float w0 = w[(4*kb+0)*256], w1 = w[(4*kb+1)*256],
                  w2 = w[(4*kb+2)*256], w3 = w[(4*kb+3)*256];
            ac0 = fmaf(w3,A0.w,fmaf(w2,A0.z,fmaf(w1,A0.y,fmaf(w0,A0.x,ac0))));
            ac1 = fmaf(w3,A1.w,fmaf(w2,A1.z,fmaf(w1,A1.y,fmaf(w0,A1.x,ac1))));
            ac2 = fmaf(w3,A2.w,fmaf(w2,A2.z,fmaf(w1,A2.y,fmaf(w0,A2.x,ac2))));
            ac3 = fmaf(w3,A3.w,fmaf(w2,A3.z,fmaf(w1,A3.y,fmaf(w0,A3.x,ac3))));
            ac4 = fmaf(w3,A4.w,fmaf(w2,A4.z,fmaf(w1,A4.y,fmaf(w0,A4.x,ac4))));
        }
        xz_s[(kq*5+0)*256+c] = ac0;  xz_s[(kq*5+1)*256+c] = ac1;
        xz_s[(kq*5+2)*256+c] = ac2;  xz_s[(kq*5+3)*256+c] = ac3;
        xz_s[(kq*5+4)*256+c] = ac4;
    }
    __syncthreads();
    for (int v = tid; v < 5*DM; v += 1024) {
        int r = v >> 8, c = v & 255;
        float acc = gb[(size_t)i*DM + c];
        #pragma unroll
        for (int kq = 0; kq < 4; ++kq) acc += xz_s[(kq*5 + r)*256 + c];
        int row = b*5 + r;
        int np  = (i == 0) ? row : (r*16 + b);
        s_g[((size_t)i*NTOK + np)*DM + c] = 1.f + silu_f(acc);
    }
}

// ---------------- fused elementwise: o = x * s[plane], plane = idx / HW --------
__global__ __launch_bounds__(256) void k_elem(
    const float* __restrict__ x1, const float* __restrict__ x2,
    const float* __restrict__ x3, const float* __restrict__ x4,
    const float* __restrict__ audio, const float* __restrict__ s_g,
    float* __restrict__ out) {
    int b = blockIdx.x;
    int t = threadIdx.x;

    if (b < 512) {
        // o4: HW=49 (odd) -> per-component plane index
        const float* s = s_g + 3 * NTOK * DM;
        const float4* xv = (const float4*)x4;
        float4* ov = (float4*)out;
        const int total4 = 1003520 / 4;
        for (int v = b * 256 + t; v < total4; v += 512 * 256) {
            float4 x = xv[v];
            float* xp = (float*)&x;
#pragma unroll
            for (int j = 0; j < 4; ++j) {
                int idx = v * 4 + j;
                xp[j] *= s[idx / 49];
            }
            ov[v] = x;
        }
    } else if (b < 1024) {
        const float* s = s_g + 2 * NTOK * DM;
        const float4* xv = (const float4*)x3;
        float4* ov = (float4*)(out + 1003520);
        const int total4 = 4014080 / 4;
        for (int v = (b - 512) * 256 + t; v < total4; v += 512 * 256) {
            float f = s[v / 49];
            float4 x = xv[v];
            x.x *= f; x.y *= f; x.z *= f; x.w *= f;
            ov[v] = x;
        }
    } else if (b < 2048) {
        const float* s = s_g + 1 * NTOK * DM;
        const float4* xv = (const float4*)x2;
        float4* ov = (float4*)(out + 5017600);
        const int total4 = 16056320 / 4;
        for (int v = (b - 1024) * 256 + t; v < total4; v += 1024 * 256) {
            float f = s[v / 196];
            float4 x = xv[v];
            x.x *= f; x.y *= f; x.z *= f; x.w *= f;
            ov[v] = x;
        }
    } else if (b < 6144) {
        const float* s = s_g;
        const float4* xv = (const float4*)x1;
        float4* ov = (float4*)(out + 21073920);
        const int total4 = 64225280 / 4;
        for (int v = (b - 2048) * 256 + t; v < total4; v += 4096 * 256) {
            float f = s[v / 784];
            float4 x = xv[v];
            x.x *= f; x.y *= f; x.z *= f; x.w *= f;
            ov[v] = x;
        }
    } else {
        int idx = (b - 6144) * 256 + t;
        out[85299200 + idx] = audio[idx];
    }
}

extern "C" void kernel_launch(void* const* d_in, const int* in_sizes, int n_in,
                              void* d_out, int out_size, void* d_ws, size_t ws_size,
                              hipStream_t stream) {
    const float* x1        = (const float*)d_in[0];
    const float* x2        = (const float*)d_in[1];
    const float* x3        = (const float*)d_in[2];
    const float* x4        = (const float*)d_in[3];
    const float* audio     = (const float*)d_in[4];
    const float* ln_g      = (const float*)d_in[5];
    const float* ln_b      = (const float*)d_in[6];
    const float* in_proj_w = (const float*)d_in[7];
    const float* conv_w    = (const float*)d_in[8];
    const float* conv_b    = (const float*)d_in[9];
    const float* xproj_w   = (const float*)d_in[10];
    const float* dt_w      = (const float*)d_in[11];
    const float* dt_b      = (const float*)d_in[12];
    const float* A_log     = (const float*)d_in[13];
    const float* Dvec      = (const float*)d_in[14];
    const float* out_proj_w= (const float*)d_in[15];
    const float* gate_w    = (const float*)d_in[16];
    const float* gate_b    = (const float*)d_in[17];

    float* ws = (float*)d_ws;

    k_tr<<<5248, 256, 0, stream>>>(in_proj_w, out_proj_w, xproj_w, gate_w, ws);
    k_chain<<<64, 1024, 0, stream>>>(audio, ln_g, ln_b, conv_w, conv_b,
                                     dt_w, dt_b, A_log, Dvec, gate_b, ws);
    k_elem<<<6224, 256, 0, stream>>>(x1, x2, x3, x4, audio, ws + OFF_SG,
                                     (float*)d_out);
}

// Round 5
// 302.160 us; speedup vs baseline: 1.8728x; 1.0623x over previous
//
#include <hip/hip_runtime.h>
#include <hip/hip_bf16.h>
#include <math.h>

// x1 (80,256,56,56) x2 (80,256,28,28) x3 (80,256,14,14) x4 (80,256,7,7)
// audio (16,5,256) -> 4 branches x 3 mamba layers -> gates scale x1..x4.
// 64 independent (branch,batch) problems -> 1 block each, LDS-resident chain.
// Weights repacked k-interleaved float4: W'[k/4][c] (float4 over 4 k's) so each
// weight load is global_load_dwordx4 with 16B lane stride = 1KB/wave contiguous.

#define NTOK 80
#define DM   256
#define DI   512

typedef float f32x4 __attribute__((ext_vector_type(4)));

__device__ __forceinline__ float silu_f(float v) {
    return v / (1.f + expf(-v));
}
__device__ __forceinline__ float dot4(float4 a, float4 b) {
    return a.x*b.x + a.y*b.y + a.z*b.z + a.w*b.w;
}

// ---- workspace layout (floats) ----
#define OFF_SG    0
#define OFF_WINT  81920      // 12 * 262144  [64 k4][1024 c] f4
#define OFF_WOUTT 3227648    // 12 * 131072  [128 k4][256 c] f4
#define OFF_WXT   4800512    // 12 * 24576   [128 k4][48 c]  f4
#define OFF_GWT   5095424    // 4  * 65536   [64 k4][256 c]  f4

// ---------------- weight repack: float4-element transpose [R][C4] -> [C4][R] ---
__global__ __launch_bounds__(256) void k_tr(const float* __restrict__ Win,
                                            const float* __restrict__ Wout,
                                            const float* __restrict__ Wx,
                                            const float* __restrict__ gw,
                                            float* __restrict__ ws) {
    int b = blockIdx.x;
    const float4* src; float4* dst; int R, C4, tile;
    if (b < 768) {                        // Win: 12 x [1024][64]f4
        int mat = b >> 6; tile = b & 63; R = 1024; C4 = 64;
        src = (const float4*)Win + (size_t)mat * 65536;
        dst = (float4*)(ws + OFF_WINT) + (size_t)mat * 65536;
    } else if (b < 1152) {                // Wout: 12 x [256][128]f4
        int bb = b - 768; int mat = bb >> 5; tile = bb & 31; R = 256; C4 = 128;
        src = (const float4*)Wout + (size_t)mat * 32768;
        dst = (float4*)(ws + OFF_WOUTT) + (size_t)mat * 32768;
    } else if (b < 1248) {                // Wx: 12 x [48][128]f4
        int bb = b - 1152; int mat = bb >> 3; tile = bb & 7; R = 48; C4 = 128;
        src = (const float4*)Wx + (size_t)mat * 6144;
        dst = (float4*)(ws + OFF_WXT) + (size_t)mat * 6144;
    } else {                              // gw: 4 x [256][64]f4
        int bb = b - 1248; int mat = bb >> 4; tile = bb & 15; R = 256; C4 = 64;
        src = (const float4*)gw + (size_t)mat * 16384;
        dst = (float4*)(ws + OFF_GWT) + (size_t)mat * 16384;
    }
    int tilesC = C4 >> 5;
    int r0 = (tile / tilesC) << 5, c0 = (tile % tilesC) << 5;
    __shared__ float4 t[32][33];
    int tx = threadIdx.x & 31, ty = threadIdx.x >> 5;
#pragma unroll
    for (int j = 0; j < 4; ++j) {
        int r = ty + j * 8;
        if (r0 + r < R) t[r][tx] = src[(size_t)(r0 + r) * C4 + c0 + tx];
    }
    __syncthreads();
#pragma unroll
    for (int j = 0; j < 4; ++j) {
        int cc = ty + j * 8;
        if (r0 + tx < R) dst[(size_t)(c0 + cc) * R + r0 + tx] = t[tx][cc];
    }
}

// ---------------- fused mamba chain + gates: 64 blocks x 1024 threads ----------
__global__ __launch_bounds__(1024, 4) void k_chain(
    const float* __restrict__ audio,
    const float* __restrict__ ln_g, const float* __restrict__ ln_b,
    const float* __restrict__ Wc,   const float* __restrict__ bc,
    const float* __restrict__ Wdt,  const float* __restrict__ bdt,
    const float* __restrict__ Alog, const float* __restrict__ Dp,
    const float* __restrict__ gb,   float* __restrict__ ws)
{
    // XCD swizzle: branch i -> XCD slots {2i, 2i+1} (XCD = blockIdx % 8)
    int g = blockIdx.x;
    int slot = g & 7;
    int i = slot >> 1;
    int b = ((g >> 3) << 1) | (slot & 1);
    int tid  = threadIdx.x;
    int lane = tid & 63;
    int wave = tid >> 6;

    float* s_g = ws + OFF_SG;

    __shared__ __align__(16) float a_s  [5*DM];
    __shared__ __align__(16) float aln_s[5*DM];
    __shared__ __align__(16) float xz_s [5*1024];  // in_proj out; reused as partials
    __shared__ __align__(16) float xc_s [5*DI];
    __shared__ __align__(16) float dbl_s[5*48];
    __shared__ __align__(16) float y_s  [5*DI];
    __shared__ __align__(16) float xp_s [4*5*48];

    if (tid < 320)
        ((float4*)a_s)[tid] = ((const float4*)(audio + (size_t)b*5*DM))[tid];
    __syncthreads();

    for (int l = 0; l < 3; ++l) {
        int il = i*3 + l;

        // ---- LayerNorm: wave w < 5 handles row w ----
        if (wave < 5) {
            float4 x = ((float4*)a_s)[wave*64 + lane];
            float s = x.x + x.y + x.z + x.w;
            #pragma unroll
            for (int o = 32; o > 0; o >>= 1) s += __shfl_down(s, o, 64);
            float mu = __shfl(s, 0, 64) * (1.f/256.f);
            float4 d = make_float4(x.x-mu, x.y-mu, x.z-mu, x.w-mu);
            float v = d.x*d.x + d.y*d.y + d.z*d.z + d.w*d.w;
            #pragma unroll
            for (int o = 32; o > 0; o >>= 1) v += __shfl_down(v, o, 64);
            float rstd = rsqrtf(__shfl(v, 0, 64) * (1.f/256.f) + 1e-5f);
            float4 g4 = ((const float4*)(ln_g + (size_t)il*DM))[lane];
            float4 b4 = ((const float4*)(ln_b + (size_t)il*DM))[lane];
            ((float4*)aln_s)[wave*64 + lane] =
                make_float4(d.x*rstd*g4.x + b4.x, d.y*rstd*g4.y + b4.y,
                            d.z*rstd*g4.z + b4.z, d.w*rstd*g4.w + b4.w);
        }
        __syncthreads();

        // ---- in_proj: col c = tid, 64 k4-steps, float4 weight loads ----
        {
            const float4* wp = (const float4*)(ws + OFF_WINT) + (size_t)il*65536 + tid;
            const float4* a4 = (const float4*)aln_s;
            float ac0=0.f, ac1=0.f, ac2=0.f, ac3=0.f, ac4=0.f;
            #pragma unroll 8
            for (int k4 = 0; k4 < 64; ++k4) {
                float4 w = wp[(size_t)k4*1024];
                float4 A0=a4[k4], A1=a4[64+k4], A2=a4[128+k4],
                       A3=a4[192+k4], A4=a4[256+k4];
                ac0 += dot4(w, A0);  ac1 += dot4(w, A1);  ac2 += dot4(w, A2);
                ac3 += dot4(w, A3);  ac4 += dot4(w, A4);
            }
            xz_s[       tid] = ac0;  xz_s[1024 + tid] = ac1;
            xz_s[2048 + tid] = ac2;  xz_s[3072 + tid] = ac3;
            xz_s[4096 + tid] = ac4;
        }
        __syncthreads();

        // ---- depthwise causal conv (k=4) + bias + SiLU ----
        for (int v = tid; v < 5*DI; v += 1024) {
            int r = v >> 9, d = v & (DI-1);
            float acc = bc[(size_t)il*DI + d];
            const float* wr = Wc + ((size_t)il*DI + d)*4;
            #pragma unroll
            for (int k = 0; k < 4; ++k) {
                int ts = r + k - 3;
                if (ts >= 0) acc += wr[k] * xz_s[ts*1024 + d];
            }
            xc_s[r*DI + d] = silu_f(acc);
        }
        __syncthreads();

        // ---- x_proj: 5x48, K split 4 over 960 threads, float4 loads ----
        if (tid < 960) {
            int c = tid % 48, r = (tid / 48) % 5, kq = tid / 240;
            const float4* wp = (const float4*)(ws + OFF_WXT) + (size_t)il*6144 + c;
            const float4* x4 = (const float4*)xc_s + r*128 + kq*32;
            float acc = 0.f;
            #pragma unroll 8
            for (int kk = 0; kk < 32; ++kk)
                acc += dot4(wp[(size_t)(kq*32 + kk)*48], x4[kk]);
            xp_s[tid] = acc;
        }
        __syncthreads();
        if (tid < 240)
            dbl_s[tid] = xp_s[tid] + xp_s[240+tid] + xp_s[480+tid] + xp_s[720+tid];
        __syncthreads();

        // ---- scan (dt-proj fused) + D skip + z gate: thread = channel ----
        if (tid < DI) {
            int d = tid;
            float A[16], h[16];
            const float4* al4 = (const float4*)(Alog + ((size_t)il*DI + d)*16);
            float4 av0 = al4[0], av1 = al4[1], av2 = al4[2], av3 = al4[3];
            A[0]=-expf(av0.x); A[1]=-expf(av0.y); A[2]=-expf(av0.z); A[3]=-expf(av0.w);
            A[4]=-expf(av1.x); A[5]=-expf(av1.y); A[6]=-expf(av1.z); A[7]=-expf(av1.w);
            A[8]=-expf(av2.x); A[9]=-expf(av2.y); A[10]=-expf(av2.z); A[11]=-expf(av2.w);
            A[12]=-expf(av3.x); A[13]=-expf(av3.y); A[14]=-expf(av3.z); A[15]=-expf(av3.w);
            #pragma unroll
            for (int n = 0; n < 16; ++n) h[n] = 0.f;
            const float4* wd4 = (const float4*)(Wdt + ((size_t)il*DI + d)*16);
            float4 w0 = wd4[0], w1 = wd4[1], w2 = wd4[2], w3 = wd4[3];
            float bdtv = bdt[(size_t)il*DI + d];
            float dv   = Dp[(size_t)il*DI + d];
            #pragma unroll
            for (int t = 0; t < 5; ++t) {
                const float* db = dbl_s + t*48;
                float acc = bdtv;
                acc += db[0]*w0.x + db[1]*w0.y + db[2]*w0.z + db[3]*w0.w;
                acc += db[4]*w1.x + db[5]*w1.y + db[6]*w1.z + db[7]*w1.w;
                acc += db[8]*w2.x + db[9]*w2.y + db[10]*w2.z + db[11]*w2.w;
                acc += db[12]*w3.x + db[13]*w3.y + db[14]*w3.z + db[15]*w3.w;
                float dtv = fmaxf(acc, 0.f) + log1pf(expf(-fabsf(acc)));
                float xv  = xc_s[t*DI + d];
                float zv  = xz_s[t*1024 + DI + d];
                float dx  = dtv * xv;
                float yacc = 0.f;
                #pragma unroll
                for (int n = 0; n < 16; ++n) {
                    h[n] = expf(dtv*A[n])*h[n] + dx*db[16 + n];
                    yacc += h[n]*db[32 + n];
                }
                y_s[t*DI + d] = (yacc + xv*dv) * silu_f(zv);
            }
        }
        __syncthreads();   // xz_s free, y_s ready

        // ---- out_proj: c = tid&255, K split 4, float4 loads ----
        {
            int c = tid & 255, kq = tid >> 8;
            const float4* wp = (const float4*)(ws + OFF_WOUTT) + (size_t)il*32768 + c;
            const float4* yy = (const float4*)y_s;   // [5][128]
            float ac0=0.f, ac1=0.f, ac2=0.f, ac3=0.f, ac4=0.f;
            #pragma unroll 8
            for (int kk = 0; kk < 32; ++kk) {
                int k4 = kq*32 + kk;
                float4 w = wp[(size_t)k4*256];
                float4 Y0=yy[k4], Y1=yy[128+k4], Y2=yy[256+k4],
                       Y3=yy[384+k4], Y4=yy[512+k4];
                ac0 += dot4(w, Y0);  ac1 += dot4(w, Y1);  ac2 += dot4(w, Y2);
                ac3 += dot4(w, Y3);  ac4 += dot4(w, Y4);
            }
            xz_s[(kq*5+0)*256+c] = ac0;  xz_s[(kq*5+1)*256+c] = ac1;
            xz_s[(kq*5+2)*256+c] = ac2;  xz_s[(kq*5+3)*256+c] = ac3;
            xz_s[(kq*5+4)*256+c] = ac4;
        }
        __syncthreads();

        // ---- reduce partials + residual ----
        for (int v = tid; v < 5*DM; v += 1024) {
            int r = v >> 8, c = v & 255;
            float sum = aln_s[r*DM + c];
            #pragma unroll
            for (int kq = 0; kq < 4; ++kq) sum += xz_s[(kq*5 + r)*256 + c];
            a_s[r*DM + c] = sum;
        }
        __syncthreads();
    }

    // ---- gates: c = tid&255, K=256 split 4; s = 1+silu(a@gw^T+gb), permuted ----
    {
        int c = tid & 255, kq = tid >> 8;
        const float4* wp = (const float4*)(ws + OFF_GWT) + (size_t)i*16384 + c;
        const float4* a4 = (const float4*)a_s;   // [5][64]
        float ac0=0.f, ac1=0.f, ac2=0.f, ac3=0.f, ac4=0.f;
        #pragma unroll 8
        for (int kk = 0; kk < 16; ++kk) {
            int k4 = kq*16 + kk;
            float4 w = wp[(size_t)k4*256];
            float4 A0=a4[k4], A1=a4[64+k4], A2=a4[128+k4],
                   A3=a4[192+k4], A4=a4[256+k4];
            ac0 += dot4(w, A0);  ac1 += dot4(w, A1);  ac2 += dot4(w, A2);
            ac3 += dot4(w, A3);  ac4 += dot4(w, A4);
        }
        xz_s[(kq*5+0)*256+c] = ac0;  xz_s[(kq*5+1)*256+c] = ac1;
        xz_s[(kq*5+2)*256+c] = ac2;  xz_s[(kq*5+3)*256+c] = ac3;
        xz_s[(kq*5+4)*256+c] = ac4;
    }
    __syncthreads();
    for (int v = tid; v < 5*DM; v += 1024) {
        int r = v >> 8, c = v & 255;
        float acc = gb[(size_t)i*DM + c];
        #pragma unroll
        for (int kq = 0; kq < 4; ++kq) acc += xz_s[(kq*5 + r)*256 + c];
        int row = b*5 + r;
        int np  = (i == 0) ? row : (r*16 + b);
        s_g[((size_t)i*NTOK + np)*DM + c] = 1.f + silu_f(acc);
    }
}

// ---------------- fused elementwise: o = x * s[plane], nontemporal streaming ---
__global__ __launch_bounds__(256) void k_elem(
    const float* __restrict__ x1, const float* __restrict__ x2,
    const float* __restrict__ x3, const float* __restrict__ x4,
    const float* __restrict__ audio, const float* __restrict__ s_g,
    float* __restrict__ out) {
    int b = blockIdx.x;
    int t = threadIdx.x;

    if (b < 512) {
        // o4: HW=49 (odd) -> per-component plane index
        const float* s = s_g + 3 * NTOK * DM;
        const f32x4* xv = (const f32x4*)x4;
        f32x4* ov = (f32x4*)out;
        const int total4 = 1003520 / 4;
        for (int v = b * 256 + t; v < total4; v += 512 * 256) {
            f32x4 x = __builtin_nontemporal_load(&xv[v]);
#pragma unroll
            for (int j = 0; j < 4; ++j) {
                int idx = v * 4 + j;
                x[j] *= s[idx / 49];
            }
            __builtin_nontemporal_store(x, &ov[v]);
        }
    } else if (b < 1024) {
        const float* s = s_g + 2 * NTOK * DM;
        const f32x4* xv = (const f32x4*)x3;
        f32x4* ov = (f32x4*)(out + 1003520);
        const int total4 = 4014080 / 4;
        for (int v = (b - 512) * 256 + t; v < total4; v += 512 * 256) {
            float f = s[v / 49];
            f32x4 x = __builtin_nontemporal_load(&xv[v]);
            x *= f;
            __builtin_nontemporal_store(x, &ov[v]);
        }
    } else if (b < 2048) {
        const float* s = s_g + 1 * NTOK * DM;
        const f32x4* xv = (const f32x4*)x2;
        f32x4* ov = (f32x4*)(out + 5017600);
        const int total4 = 16056320 / 4;
        for (int v = (b - 1024) * 256 + t; v < total4; v += 1024 * 256) {
            float f = s[v / 196];
            f32x4 x = __builtin_nontemporal_load(&xv[v]);
            x *= f;
            __builtin_nontemporal_store(x, &ov[v]);
        }
    } else if (b < 6144) {
        const float* s = s_g;
        const f32x4* xv = (const f32x4*)x1;
        f32x4* ov = (f32x4*)(out + 21073920);
        const int total4 = 64225280 / 4;
        for (int v = (b - 2048) * 256 + t; v < total4; v += 4096 * 256) {
            float f = s[v / 784];
            f32x4 x = __builtin_nontemporal_load(&xv[v]);
            x *= f;
            __builtin_nontemporal_store(x, &ov[v]);
        }
    } else {
        int idx = (b - 6144) * 256 + t;
        out[85299200 + idx] = audio[idx];
    }
}

extern "C" void kernel_launch(void* const* d_in, const int* in_sizes, int n_in,
                              void* d_out, int out_size, void* d_ws, size_t ws_size,
                              hipStream_t stream) {
    const float* x1        = (const float*)d_in[0];
    const float* x2        = (const float*)d_in[1];
    const float* x3        = (const float*)d_in[2];
    const float* x4        = (const float*)d_in[3];
    const float* audio     = (const float*)d_in[4];
    const float* ln_g      = (const float*)d_in[5];
    const float* ln_b      = (const float*)d_in[6];
    const float* in_proj_w = (const float*)d_in[7];
    const float* conv_w    = (const float*)d_in[8];
    const float* conv_b    = (const float*)d_in[9];
    const float* xproj_w   = (const float*)d_in[10];
    const float* dt_w      = (const float*)d_in[11];
    const float* dt_b      = (const float*)d_in[12];
    const float* A_log     = (const float*)d_in[13];
    const float* Dvec      = (const float*)d_in[14];
    const float* out_proj_w= (const float*)d_in[15];
    const float* gate_w    = (const float*)d_in[16];
    const float* gate_b    = (const float*)d_in[17];

    float* ws = (float*)d_ws;

    k_tr<<<1312, 256, 0, stream>>>(in_proj_w, out_proj_w, xproj_w, gate_w, ws);
    k_chain<<<64, 1024, 0, stream>>>(audio, ln_g, ln_b, conv_w, conv_b,
                                     dt_w, dt_b, A_log, Dvec, gate_b, ws);
    k_elem<<<6224, 256, 0, stream>>>(x1, x2, x3, x4, audio, ws + OFF_SG,
                                     (float*)d_out);
}

// Round 6
// 252.359 us; speedup vs baseline: 2.2424x; 1.1973x over previous
//
#include <hip/hip_runtime.h>
#include <hip/hip_bf16.h>
#include <math.h>

// audio (16,5,256) -> 4 branches x 3 mamba layers -> gates scale x1..x4.
// Chain split 4-ways per (branch,batch): 256 blocks x 512 threads (full chip).
// Member q owns d_inner slice [128q,128q+128): in_proj/conv/scan slice-local in
// LDS; only dbl (240 f) and out_proj partials (1280 f) cross blocks via ws +
// agent-scope 4-member barriers. Weights k-interleaved float4 (coalesced).

#define NTOK 80
#define DM   256
#define DI   512

typedef float f32x4 __attribute__((ext_vector_type(4)));

__device__ __forceinline__ float silu_f(float v) {
    return v / (1.f + expf(-v));
}
__device__ __forceinline__ float dot4(float4 a, float4 b) {
    return a.x*b.x + a.y*b.y + a.z*b.z + a.w*b.w;
}

// ---- workspace layout (float indices) ----
#define OFF_SG    0          // 81920
#define OFF_WINT  81920      // 12 * 262144   [64 k4][1024 c] f4
#define OFF_WOUTT 3227648    // 12 * 131072   [128 k4][256 c] f4
#define OFF_WXT   4800512    // 12 * 24576    [128 k4][48 c]  f4
#define OFF_GWT   5095424    // 4  * 65536    [64 k4][256 c]  f4
#define OFF_DBLP  5357568    // 64 groups * 4 q * 240
#define OFF_OUTP  5419008    // 64 groups * 4 q * 1280
#define OFF_BAR   5746688    // 512 uints

// ---------------- weight repack: float4-element transpose [R][C4] -> [C4][R] ---
__global__ __launch_bounds__(256) void k_tr(const float* __restrict__ Win,
                                            const float* __restrict__ Wout,
                                            const float* __restrict__ Wx,
                                            const float* __restrict__ gw,
                                            float* __restrict__ ws) {
    if (blockIdx.x == 0 && threadIdx.x < 256) {   // zero group-barrier counters
        unsigned* barp = (unsigned*)(ws + OFF_BAR);
        barp[threadIdx.x] = 0u;
        barp[256 + threadIdx.x] = 0u;
    }
    int b = blockIdx.x;
    const float4* src; float4* dst; int R, C4, tile;
    if (b < 768) {                        // Win: 12 x [1024][64]f4
        int mat = b >> 6; tile = b & 63; R = 1024; C4 = 64;
        src = (const float4*)Win + (size_t)mat * 65536;
        dst = (float4*)(ws + OFF_WINT) + (size_t)mat * 65536;
    } else if (b < 1152) {                // Wout: 12 x [256][128]f4
        int bb = b - 768; int mat = bb >> 5; tile = bb & 31; R = 256; C4 = 128;
        src = (const float4*)Wout + (size_t)mat * 32768;
        dst = (float4*)(ws + OFF_WOUTT) + (size_t)mat * 32768;
    } else if (b < 1248) {                // Wx: 12 x [48][128]f4
        int bb = b - 1152; int mat = bb >> 3; tile = bb & 7; R = 48; C4 = 128;
        src = (const float4*)Wx + (size_t)mat * 6144;
        dst = (float4*)(ws + OFF_WXT) + (size_t)mat * 6144;
    } else {                              // gw: 4 x [256][64]f4
        int bb = b - 1248; int mat = bb >> 4; tile = bb & 15; R = 256; C4 = 64;
        src = (const float4*)gw + (size_t)mat * 16384;
        dst = (float4*)(ws + OFF_GWT) + (size_t)mat * 16384;
    }
    int tilesC = C4 >> 5;
    int r0 = (tile / tilesC) << 5, c0 = (tile % tilesC) << 5;
    __shared__ float4 t[32][33];
    int tx = threadIdx.x & 31, ty = threadIdx.x >> 5;
#pragma unroll
    for (int j = 0; j < 4; ++j) {
        int r = ty + j * 8;
        if (r0 + r < R) t[r][tx] = src[(size_t)(r0 + r) * C4 + c0 + tx];
    }
    __syncthreads();
#pragma unroll
    for (int j = 0; j < 4; ++j) {
        int cc = ty + j * 8;
        if (r0 + tx < R) dst[(size_t)(c0 + cc) * R + r0 + tx] = t[tx][cc];
    }
}

// 4-member group barrier; agent scope so correctness is XCD-placement-free.
__device__ __forceinline__ void gbar(unsigned* slot) {
    __syncthreads();   // all threads' global stores complete (vmcnt drained)
    if (threadIdx.x == 0) {
        __hip_atomic_fetch_add(slot, 1u, __ATOMIC_RELEASE, __HIP_MEMORY_SCOPE_AGENT);
        while (__hip_atomic_load(slot, __ATOMIC_RELAXED, __HIP_MEMORY_SCOPE_AGENT) < 4u)
            __builtin_amdgcn_s_sleep(1);
        (void)__hip_atomic_load(slot, __ATOMIC_ACQUIRE, __HIP_MEMORY_SCOPE_AGENT);
    }
    __syncthreads();
}

// ---------------- split mamba chain + gates: 256 blocks x 512 threads ----------
__global__ __launch_bounds__(512) void k_chain4(
    const float* __restrict__ audio,
    const float* __restrict__ ln_g, const float* __restrict__ ln_b,
    const float* __restrict__ Wc,   const float* __restrict__ bc,
    const float* __restrict__ Wdt,  const float* __restrict__ bdt,
    const float* __restrict__ Alog, const float* __restrict__ Dp,
    const float* __restrict__ gb,   float* __restrict__ ws)
{
    int gid = blockIdx.x & 63;    // group = (branch,batch)
    int q   = blockIdx.x >> 6;    // member 0..3 (blockIdx = gid + 64q: same XCD)
    int i = gid & 3, b = gid >> 2;
    int tid = threadIdx.x, lane = tid & 63, wave = tid >> 6;
    int dq = q * 128;             // own d_inner slice start

    float* s_g  = ws + OFF_SG;
    float* dblp = ws + OFF_DBLP + (size_t)gid * 4 * 240;
    float* outp = ws + OFF_OUTP + (size_t)gid * 4 * 1280;
    unsigned* bar = (unsigned*)(ws + OFF_BAR) + gid * 8;

    __shared__ __align__(16) float a_l   [1280];  // activations (5x256), redundant
    __shared__ __align__(16) float aln_l [1280];  // LN out, redundant
    __shared__ __align__(16) float xz_l  [1280];  // own cols: [r][0..127]=xc-part, [r][128..255]=z
    __shared__ __align__(16) float xc_l  [640];   // conv+silu out, own 128 d
    __shared__ __align__(16) float y_l   [640];   // scan out, own 128 d
    __shared__ __align__(16) float dbl_l [240];
    __shared__ __align__(16) float part_l[2560];  // intra-block K-split scratch

    for (int v = tid; v < 320; v += 512)
        ((float4*)a_l)[v] = ((const float4*)(audio + (size_t)b * 1280))[v];
    __syncthreads();

    for (int l = 0; l < 3; ++l) {
        int il = i * 3 + l;

        // ---- LayerNorm (redundant in each member): wave w<5 handles row w ----
        if (wave < 5) {
            float4 x = ((float4*)a_l)[wave*64 + lane];
            float s = x.x + x.y + x.z + x.w;
            #pragma unroll
            for (int o = 32; o > 0; o >>= 1) s += __shfl_down(s, o, 64);
            float mu = __shfl(s, 0, 64) * (1.f/256.f);
            float4 d = make_float4(x.x-mu, x.y-mu, x.z-mu, x.w-mu);
            float v2 = d.x*d.x + d.y*d.y + d.z*d.z + d.w*d.w;
            #pragma unroll
            for (int o = 32; o > 0; o >>= 1) v2 += __shfl_down(v2, o, 64);
            float rstd = rsqrtf(__shfl(v2, 0, 64) * (1.f/256.f) + 1e-5f);
            float4 g4 = ((const float4*)(ln_g + (size_t)il*DM))[lane];
            float4 b4 = ((const float4*)(ln_b + (size_t)il*DM))[lane];
            ((float4*)aln_l)[wave*64 + lane] =
                make_float4(d.x*rstd*g4.x + b4.x, d.y*rstd*g4.y + b4.y,
                            d.z*rstd*g4.z + b4.z, d.w*rstd*g4.w + b4.w);
        }
        __syncthreads();

        // ---- in_proj: own 256 cols, K=256 split 2 (kh) ----
        {
            int cl = tid & 255, kh = tid >> 8;
            int gcol = (cl < 128) ? (dq + cl) : (384 + dq + cl);  // xc | z cols
            const float4* wp = (const float4*)(ws + OFF_WINT) + (size_t)il*65536 + gcol;
            const float4* a4 = (const float4*)aln_l;
            float ac0=0.f, ac1=0.f, ac2=0.f, ac3=0.f, ac4=0.f;
            #pragma unroll 8
            for (int kk = 0; kk < 32; ++kk) {
                int k4 = kh*32 + kk;
                float4 w = wp[(size_t)k4*1024];
                ac0 += dot4(w, a4[k4]);      ac1 += dot4(w, a4[64+k4]);
                ac2 += dot4(w, a4[128+k4]);  ac3 += dot4(w, a4[192+k4]);
                ac4 += dot4(w, a4[256+k4]);
            }
            part_l[kh*1280 +       cl] = ac0;  part_l[kh*1280 + 256 + cl] = ac1;
            part_l[kh*1280 + 512 + cl] = ac2;  part_l[kh*1280 + 768 + cl] = ac3;
            part_l[kh*1280 +1024 + cl] = ac4;
        }
        __syncthreads();
        for (int v = tid; v < 1280; v += 512) xz_l[v] = part_l[v] + part_l[1280 + v];
        __syncthreads();

        // ---- depthwise causal conv (k=4) + bias + SiLU on own 128 d ----
        for (int v = tid; v < 640; v += 512) {
            int r = v >> 7, dl = v & 127;
            int d = dq + dl;
            float acc = bc[(size_t)il*DI + d];
            const float* wr = Wc + ((size_t)il*DI + d)*4;
            #pragma unroll
            for (int k = 0; k < 4; ++k) {
                int ts = r + k - 3;
                if (ts >= 0) acc += wr[k] * xz_l[ts*256 + dl];
            }
            xc_l[r*128 + dl] = silu_f(acc);
        }
        __syncthreads();

        // ---- x_proj partial over own K=128 (2-way kh split, 480 threads) ----
        if (tid < 480) {
            int c = tid % 48, r = (tid / 48) % 5, kh = tid / 240;
            const float4* wp = (const float4*)(ws + OFF_WXT) + (size_t)il*6144 + c;
            const float4* x4 = (const float4*)xc_l + r*32 + kh*16;
            float acc = 0.f;
            #pragma unroll 8
            for (int kk = 0; kk < 16; ++kk)
                acc += dot4(wp[(size_t)(q*32 + kh*16 + kk)*48], x4[kk]);
            part_l[tid] = acc;
        }
        __syncthreads();
        if (tid < 240) dblp[q*240 + tid] = part_l[tid] + part_l[240 + tid];
        gbar(bar + l*2);
        if (tid < 240)
            dbl_l[tid] = dblp[tid] + dblp[240+tid] + dblp[480+tid] + dblp[720+tid];
        __syncthreads();

        // ---- scan (dt-proj fused) + D skip + z gate on own 128 d ----
        if (tid < 128) {
            int d = dq + tid;
            float A[16], h[16];
            const float4* al4 = (const float4*)(Alog + ((size_t)il*DI + d)*16);
            float4 av0 = al4[0], av1 = al4[1], av2 = al4[2], av3 = al4[3];
            A[0]=-expf(av0.x); A[1]=-expf(av0.y); A[2]=-expf(av0.z); A[3]=-expf(av0.w);
            A[4]=-expf(av1.x); A[5]=-expf(av1.y); A[6]=-expf(av1.z); A[7]=-expf(av1.w);
            A[8]=-expf(av2.x); A[9]=-expf(av2.y); A[10]=-expf(av2.z); A[11]=-expf(av2.w);
            A[12]=-expf(av3.x); A[13]=-expf(av3.y); A[14]=-expf(av3.z); A[15]=-expf(av3.w);
            #pragma unroll
            for (int n = 0; n < 16; ++n) h[n] = 0.f;
            const float4* wd4 = (const float4*)(Wdt + ((size_t)il*DI + d)*16);
            float4 w0 = wd4[0], w1 = wd4[1], w2 = wd4[2], w3 = wd4[3];
            float bdtv = bdt[(size_t)il*DI + d];
            float dv   = Dp[(size_t)il*DI + d];
            #pragma unroll
            for (int t = 0; t < 5; ++t) {
                const float* db = dbl_l + t*48;
                float acc = bdtv;
                acc += db[0]*w0.x + db[1]*w0.y + db[2]*w0.z + db[3]*w0.w;
                acc += db[4]*w1.x + db[5]*w1.y + db[6]*w1.z + db[7]*w1.w;
                acc += db[8]*w2.x + db[9]*w2.y + db[10]*w2.z + db[11]*w2.w;
                acc += db[12]*w3.x + db[13]*w3.y + db[14]*w3.z + db[15]*w3.w;
                float dtv = fmaxf(acc, 0.f) + log1pf(expf(-fabsf(acc)));
                float xv  = xc_l[t*128 + tid];
                float zv  = xz_l[t*256 + 128 + tid];
                float dx  = dtv * xv;
                float yacc = 0.f;
                #pragma unroll
                for (int n = 0; n < 16; ++n) {
                    h[n] = expf(dtv*A[n])*h[n] + dx*db[16 + n];
                    yacc += h[n]*db[32 + n];
                }
                y_l[t*128 + tid] = (yacc + xv*dv) * silu_f(zv);
            }
        }
        __syncthreads();

        // ---- out_proj partial: 256 cols, own K=128 split 2 (kh) ----
        {
            int c = tid & 255, kh = tid >> 8;
            const float4* wp = (const float4*)(ws + OFF_WOUTT) + (size_t)il*32768 + c;
            const float4* yy = (const float4*)y_l;   // [5][32]
            float ac0=0.f, ac1=0.f, ac2=0.f, ac3=0.f, ac4=0.f;
            #pragma unroll 8
            for (int kk = 0; kk < 16; ++kk) {
                int k4 = q*32 + kh*16 + kk;
                int yk = kh*16 + kk;
                float4 w = wp[(size_t)k4*256];
                ac0 += dot4(w, yy[yk]);      ac1 += dot4(w, yy[32+yk]);
                ac2 += dot4(w, yy[64+yk]);   ac3 += dot4(w, yy[96+yk]);
                ac4 += dot4(w, yy[128+yk]);
            }
            part_l[kh*1280 +       c] = ac0;  part_l[kh*1280 + 256 + c] = ac1;
            part_l[kh*1280 + 512 + c] = ac2;  part_l[kh*1280 + 768 + c] = ac3;
            part_l[kh*1280 +1024 + c] = ac4;
        }
        __syncthreads();
        for (int v = tid; v < 1280; v += 512)
            outp[q*1280 + v] = part_l[v] + part_l[1280 + v];
        gbar(bar + l*2 + 1);
        for (int v = tid; v < 1280; v += 512)
            a_l[v] = aln_l[v] + outp[v] + outp[1280+v] + outp[2560+v] + outp[3840+v];
        __syncthreads();
    }

    // ---- gates: own 64 cols, K=256 split 8 (kq); write s_g permuted ----
    {
        int cl = tid & 63, kq = tid >> 6;
        int cg = q*64 + cl;
        const float4* wp = (const float4*)(ws + OFF_GWT) + (size_t)i*16384 + cg;
        const float4* a4 = (const float4*)a_l;   // [5][64] f4
        float ac0=0.f, ac1=0.f, ac2=0.f, ac3=0.f, ac4=0.f;
        #pragma unroll 8
        for (int kk = 0; kk < 8; ++kk) {
            int k4 = kq*8 + kk;
            float4 w = wp[(size_t)k4*256];
            ac0 += dot4(w, a4[k4]);      ac1 += dot4(w, a4[64+k4]);
            ac2 += dot4(w, a4[128+k4]);  ac3 += dot4(w, a4[192+k4]);
            ac4 += dot4(w, a4[256+k4]);
        }
        part_l[kq*320 +       cl] = ac0;  part_l[kq*320 +  64 + cl] = ac1;
        part_l[kq*320 + 128 + cl] = ac2;  part_l[kq*320 + 192 + cl] = ac3;
        part_l[kq*320 + 256 + cl] = ac4;
    }
    __syncthreads();
    for (int v = tid; v < 320; v += 512) {
        int r = v >> 6, cl = v & 63;
        int cg = q*64 + cl;
        float acc = gb[(size_t)i*DM + cg];
        #pragma unroll
        for (int kq = 0; kq < 8; ++kq) acc += part_l[kq*320 + v];
        int row = b*5 + r;
        int np  = (i == 0) ? row : (r*16 + b);
        s_g[((size_t)i*NTOK + np)*DM + cg] = 1.f + silu_f(acc);
    }
}

// ---------------- fused elementwise: o = x * s[plane], nontemporal streaming ---
__global__ __launch_bounds__(256) void k_elem(
    const float* __restrict__ x1, const float* __restrict__ x2,
    const float* __restrict__ x3, const float* __restrict__ x4,
    const float* __restrict__ audio, const float* __restrict__ s_g,
    float* __restrict__ out) {
    int b = blockIdx.x;
    int t = threadIdx.x;

    if (b < 512) {
        // o4: HW=49 (odd) -> per-component plane index
        const float* s = s_g + 3 * NTOK * DM;
        const f32x4* xv = (const f32x4*)x4;
        f32x4* ov = (f32x4*)out;
        const int total4 = 1003520 / 4;
        for (int v = b * 256 + t; v < total4; v += 512 * 256) {
            f32x4 x = __builtin_nontemporal_load(&xv[v]);
#pragma unroll
            for (int j = 0; j < 4; ++j) {
                int idx = v * 4 + j;
                x[j] *= s[idx / 49];
            }
            __builtin_nontemporal_store(x, &ov[v]);
        }
    } else if (b < 1024) {
        const float* s = s_g + 2 * NTOK * DM;
        const f32x4* xv = (const f32x4*)x3;
        f32x4* ov = (f32x4*)(out + 1003520);
        const int total4 = 4014080 / 4;
        for (int v = (b - 512) * 256 + t; v < total4; v += 512 * 256) {
            float f = s[v / 49];
            f32x4 x = __builtin_nontemporal_load(&xv[v]);
            x *= f;
            __builtin_nontemporal_store(x, &ov[v]);
        }
    } else if (b < 2048) {
        const float* s = s_g + 1 * NTOK * DM;
        const f32x4* xv = (const f32x4*)x2;
        f32x4* ov = (f32x4*)(out + 5017600);
        const int total4 = 16056320 / 4;
        for (int v = (b - 1024) * 256 + t; v < total4; v += 1024 * 256) {
            float f = s[v / 196];
            f32x4 x = __builtin_nontemporal_load(&xv[v]);
            x *= f;
            __builtin_nontemporal_store(x, &ov[v]);
        }
    } else if (b < 6144) {
        const float* s = s_g;
        const f32x4* xv = (const f32x4*)x1;
        f32x4* ov = (f32x4*)(out + 21073920);
        const int total4 = 64225280 / 4;
        for (int v = (b - 2048) * 256 + t; v < total4; v += 4096 * 256) {
            float f = s[v / 784];
            f32x4 x = __builtin_nontemporal_load(&xv[v]);
            x *= f;
            __builtin_nontemporal_store(x, &ov[v]);
        }
    } else {
        int idx = (b - 6144) * 256 + t;
        out[85299200 + idx] = audio[idx];
    }
}

extern "C" void kernel_launch(void* const* d_in, const int* in_sizes, int n_in,
                              void* d_out, int out_size, void* d_ws, size_t ws_size,
                              hipStream_t stream) {
    const float* x1        = (const float*)d_in[0];
    const float* x2        = (const float*)d_in[1];
    const float* x3        = (const float*)d_in[2];
    const float* x4        = (const float*)d_in[3];
    const float* audio     = (const float*)d_in[4];
    const float* ln_g      = (const float*)d_in[5];
    const float* ln_b      = (const float*)d_in[6];
    const float* in_proj_w = (const float*)d_in[7];
    const float* conv_w    = (const float*)d_in[8];
    const float* conv_b    = (const float*)d_in[9];
    const float* xproj_w   = (const float*)d_in[10];
    const float* dt_w      = (const float*)d_in[11];
    const float* dt_b      = (const float*)d_in[12];
    const float* A_log     = (const float*)d_in[13];
    const float* Dvec      = (const float*)d_in[14];
    const float* out_proj_w= (const float*)d_in[15];
    const float* gate_w    = (const float*)d_in[16];
    const float* gate_b    = (const float*)d_in[17];

    float* ws = (float*)d_ws;

    k_tr<<<1312, 256, 0, stream>>>(in_proj_w, out_proj_w, xproj_w, gate_w, ws);
    k_chain4<<<256, 512, 0, stream>>>(audio, ln_g, ln_b, conv_w, conv_b,
                                      dt_w, dt_b, A_log, Dvec, gate_b, ws);
    k_elem<<<6224, 256, 0, stream>>>(x1, x2, x3, x4, audio, ws + OFF_SG,
                                     (float*)d_out);
}